// Round 1
// baseline (3359.429 us; speedup 1.0000x reference)
//
#include <hip/hip_runtime.h>
#include <math.h>

// Problem constants
#define S_LEN 2048
#define NHEAD 16
#define EMB   2048
#define HD    128
#define HD2   64
#define KDIM  2048   // reduction dim of qkv GEMM (= E)
// d_out layout (floats): y [0, 8388608) | k [8388608, 16777216) | v [16777216, 25165824)
#define Y_OFF 0
#define K_OFF 8388608
#define V_OFF 16777216

// ---------------------------------------------------------------------------
// Kernel 1: qkv = x @ Wc^T + bc, fused with rope-scale + scatter.
// Only 4096 "reduced" columns are computed:
//   col' in [0,1024)    -> q, h=col'>>6, d2=col'&63  (src Wc row h*128+d2)
//   col' in [1024,2048) -> k, likewise (+E)
//   col' in [2048,4096) -> v, all 2048 dims (+2E)
// Accumulation: single fp32 accumulator per output, strictly increasing k,
// fmaf each step (matches BLAS sgemm element-wise accumulation order).
// ---------------------------------------------------------------------------
__global__ __launch_bounds__(256) void gemm_rope_kernel(
    const float* __restrict__ x, const float* __restrict__ Wc,
    const float* __restrict__ bc, const float* __restrict__ fq,
    float* __restrict__ qws, float* __restrict__ out)
{
    __shared__ __align__(16) float As[32][68];  // k-major, padded stride 68 (=17*4 floats, 16B aligned rows)
    __shared__ __align__(16) float Bs[32][68];

    const int t  = threadIdx.x;
    const int bx = blockIdx.x;   // reduced-col tile, 0..63
    const int by = blockIdx.y;   // row tile, 0..63
    const int tx = t & 15, ty = t >> 4;

    float acc[4][4] = {{0.f, 0.f, 0.f, 0.f}, {0.f, 0.f, 0.f, 0.f},
                       {0.f, 0.f, 0.f, 0.f}, {0.f, 0.f, 0.f, 0.f}};

    for (int k0 = 0; k0 < KDIM; k0 += 32) {
        #pragma unroll
        for (int p = 0; p < 2; ++p) {
            const int id  = t + (p << 8);    // 0..511
            const int row = id >> 3;         // 0..63
            const int kc  = (id & 7) << 2;   // 0..28
            float4 va = *(const float4*)(x + (by * 64 + row) * KDIM + k0 + kc);
            As[kc + 0][row] = va.x; As[kc + 1][row] = va.y;
            As[kc + 2][row] = va.z; As[kc + 3][row] = va.w;

            const int c = bx * 64 + row;     // reduced col id
            int srow;
            if (c < 1024)      srow = ((c >> 6) << 7) + (c & 63);
            else if (c < 2048) srow = 2048 + (((c - 1024) >> 6) << 7) + (c & 63);
            else               srow = 4096 + (c - 2048);
            float4 vb = *(const float4*)(Wc + srow * KDIM + k0 + kc);
            Bs[kc + 0][row] = vb.x; Bs[kc + 1][row] = vb.y;
            Bs[kc + 2][row] = vb.z; Bs[kc + 3][row] = vb.w;
        }
        __syncthreads();
        #pragma unroll
        for (int kk = 0; kk < 32; ++kk) {
            float4 a = *(const float4*)(&As[kk][ty << 2]);
            float4 b = *(const float4*)(&Bs[kk][tx << 2]);
            const float av[4] = {a.x, a.y, a.z, a.w};
            const float bv[4] = {b.x, b.y, b.z, b.w};
            #pragma unroll
            for (int i = 0; i < 4; ++i)
                #pragma unroll
                for (int j = 0; j < 4; ++j)
                    acc[i][j] = fmaf(av[i], bv[j], acc[i][j]);
        }
        __syncthreads();
    }

    float* kout = out + K_OFF;
    float* vout = out + V_OFF;
    #pragma unroll
    for (int i = 0; i < 4; ++i) {
        const int r = by * 64 + (ty << 2) + i;   // global row = b*S+s
        const int b = r >> 11, s = r & 2047;
        #pragma unroll
        for (int j = 0; j < 4; ++j) {
            const int c = bx * 64 + (tx << 2) + j;
            if (c < 2048) {
                const int sec = c >> 10;         // 0=q, 1=k
                const int cc  = c & 1023;
                const int h = cc >> 6, d2 = cc & 63;
                const float val = (acc[i][j] + bc[sec * 2048 + h * 128 + d2]) * fq[s * 64 + d2];
                const int o = ((b * 16 + h) * 2048 + s) * 128 + d2;
                if (sec == 0) { qws[o] = val;  qws[o + 64] = val; }
                else          { kout[o] = val; kout[o + 64] = val; }
            } else {
                const int cc = c - 2048;
                const int h = cc >> 7, d = cc & 127;
                vout[((b * 16 + h) * 2048 + s) * 128 + d] = acc[i][j] + bc[4096 + cc];
            }
        }
    }
}

// ---------------------------------------------------------------------------
// Kernel 2: flash attention, fp32. One block = 64 q rows of one (b,h).
// 256 threads: thread t -> q row (t>>2), d-slice (t&3)*32.
// K/V tiles of 32 keys staged in LDS. Online softmax in fp32, expf,
// scale applied once after the dot (matches reference order).
// ---------------------------------------------------------------------------
__global__ __launch_bounds__(256) void attn_kernel(
    const float* __restrict__ qws, const float* __restrict__ kbuf,
    const float* __restrict__ vbuf, float* __restrict__ y)
{
    __shared__ __align__(16) float kt[32][128];
    __shared__ __align__(16) float vt[32][128];

    const int t  = threadIdx.x;
    const int qb = blockIdx.x & 31;      // q block within head
    const int bh = blockIdx.x >> 5;      // b*16+h
    const int r  = t >> 2;               // q row in block
    const int sl = (t & 3) << 5;         // d slice start
    const int s  = (qb << 6) + r;

    float qv[32];
    {
        const float* qp = qws + (bh * 2048 + s) * 128 + sl;
        #pragma unroll
        for (int i = 0; i < 32; i += 4) {
            float4 v4 = *(const float4*)(qp + i);
            qv[i] = v4.x; qv[i + 1] = v4.y; qv[i + 2] = v4.z; qv[i + 3] = v4.w;
        }
    }

    float o[32];
    #pragma unroll
    for (int i = 0; i < 32; ++i) o[i] = 0.f;
    float m = -INFINITY, l = 0.f;

    const float* kb = kbuf + bh * (2048 * 128);
    const float* vb = vbuf + bh * (2048 * 128);

    for (int k0 = 0; k0 < 2048; k0 += 32) {
        #pragma unroll
        for (int p = 0; p < 4; ++p) {
            const int id = t + (p << 8);         // 0..1023
            const int kr = id >> 5, kc = (id & 31) << 2;
            *(float4*)(&kt[kr][kc]) = *(const float4*)(kb + (k0 + kr) * 128 + kc);
            *(float4*)(&vt[kr][kc]) = *(const float4*)(vb + (k0 + kr) * 128 + kc);
        }
        __syncthreads();

        float lg[32];
        for (int j = 0; j < 32; ++j) {
            float p = 0.f;
            const float* krow = &kt[j][sl];
            #pragma unroll
            for (int i = 0; i < 32; ++i) p = fmaf(qv[i], krow[i], p);
            p += __shfl_xor(p, 1);
            p += __shfl_xor(p, 2);
            lg[j] = p * 0.08838834764831845f;   // 1/sqrt(128), applied after dot
        }

        float mx = m;
        #pragma unroll
        for (int j = 0; j < 32; ++j) mx = fmaxf(mx, lg[j]);
        const float alpha = expf(m - mx);       // 0 on first tile (m = -inf)
        m = mx;

        float psum = 0.f;
        for (int j = 0; j < 32; ++j) { lg[j] = expf(lg[j] - mx); psum += lg[j]; }
        l = l * alpha + psum;

        #pragma unroll
        for (int i = 0; i < 32; ++i) o[i] *= alpha;
        for (int j = 0; j < 32; ++j) {
            const float pj = lg[j];
            const float* vrow = &vt[j][sl];
            #pragma unroll
            for (int i = 0; i < 32; ++i) o[i] = fmaf(pj, vrow[i], o[i]);
        }
        __syncthreads();
    }

    const float inv = 1.f / l;
    const int b = bh >> 4, h = bh & 15;
    float* yp = y + (b * 2048 + s) * 2048 + h * 128 + sl;
    #pragma unroll
    for (int i = 0; i < 32; ++i) yp[i] = o[i] * inv;
}

extern "C" void kernel_launch(void* const* d_in, const int* in_sizes, int n_in,
                              void* d_out, int out_size, void* d_ws, size_t ws_size,
                              hipStream_t stream)
{
    const float* x  = (const float*)d_in[0];   // (B,S,E) fp32
    const float* Wc = (const float*)d_in[1];   // (3E,E) fp32
    const float* bc = (const float*)d_in[2];   // (3E,)
    const float* fq = (const float*)d_in[3];   // (S, 64)
    float* out = (float*)d_out;
    float* qws = (float*)d_ws;                 // q, (B,H,S,D) fp32 = 64 MiB

    dim3 g1(64, 64);  // x: reduced-col tiles, y: row tiles
    gemm_rope_kernel<<<g1, 256, 0, stream>>>(x, Wc, bc, fq, qws, out);
    attn_kernel<<<1024, 256, 0, stream>>>(qws, out + K_OFF, out + V_OFF, out + Y_OFF);
}

// Round 2
// 3092.504 us; speedup vs baseline: 1.0863x; 1.0863x over previous
//
#include <hip/hip_runtime.h>
#include <math.h>

// Problem constants
#define S_LEN 2048
#define NHEAD 16
#define EMB   2048
#define HD    128
#define HD2   64
#define KDIM  2048   // reduction dim of qkv GEMM (= E)
// d_out layout (floats): y [0, 8388608) | k [8388608, 16777216) | v [16777216, 25165824)
#define Y_OFF 0
#define K_OFF 8388608
#define V_OFF 16777216

// ---------------------------------------------------------------------------
// Kernel 1: qkv = x @ Wc^T + bc, fused with rope-scale + scatter.
// Only 4096 "reduced" columns are computed:
//   col' in [0,1024)    -> q, h=col'>>6, d2=col'&63  (src Wc row h*128+d2)
//   col' in [1024,2048) -> k, likewise (+E)
//   col' in [2048,4096) -> v, all 2048 dims (+2E)
// ---------------------------------------------------------------------------
__global__ __launch_bounds__(256) void gemm_rope_kernel(
    const float* __restrict__ x, const float* __restrict__ Wc,
    const float* __restrict__ bc, const float* __restrict__ fq,
    float* __restrict__ qws, float* __restrict__ out)
{
    __shared__ __align__(16) float As[32][68];  // k-major, padded
    __shared__ __align__(16) float Bs[32][68];

    const int t  = threadIdx.x;
    const int bx = blockIdx.x;   // reduced-col tile, 0..63
    const int by = blockIdx.y;   // row tile, 0..63
    const int tx = t & 15, ty = t >> 4;

    float acc[4][4] = {{0.f, 0.f, 0.f, 0.f}, {0.f, 0.f, 0.f, 0.f},
                       {0.f, 0.f, 0.f, 0.f}, {0.f, 0.f, 0.f, 0.f}};

    for (int k0 = 0; k0 < KDIM; k0 += 32) {
        #pragma unroll
        for (int p = 0; p < 2; ++p) {
            const int id  = t + (p << 8);    // 0..511
            const int row = id >> 3;         // 0..63
            const int kc  = (id & 7) << 2;   // 0..28
            float4 va = *(const float4*)(x + (by * 64 + row) * KDIM + k0 + kc);
            As[kc + 0][row] = va.x; As[kc + 1][row] = va.y;
            As[kc + 2][row] = va.z; As[kc + 3][row] = va.w;

            const int c = bx * 64 + row;     // reduced col id
            int srow;
            if (c < 1024)      srow = ((c >> 6) << 7) + (c & 63);
            else if (c < 2048) srow = 2048 + (((c - 1024) >> 6) << 7) + (c & 63);
            else               srow = 4096 + (c - 2048);
            float4 vb = *(const float4*)(Wc + srow * KDIM + k0 + kc);
            Bs[kc + 0][row] = vb.x; Bs[kc + 1][row] = vb.y;
            Bs[kc + 2][row] = vb.z; Bs[kc + 3][row] = vb.w;
        }
        __syncthreads();
        #pragma unroll
        for (int kk = 0; kk < 32; ++kk) {
            float4 a = *(const float4*)(&As[kk][ty << 2]);
            float4 b = *(const float4*)(&Bs[kk][tx << 2]);
            const float av[4] = {a.x, a.y, a.z, a.w};
            const float bv[4] = {b.x, b.y, b.z, b.w};
            #pragma unroll
            for (int i = 0; i < 4; ++i)
                #pragma unroll
                for (int j = 0; j < 4; ++j)
                    acc[i][j] = fmaf(av[i], bv[j], acc[i][j]);
        }
        __syncthreads();
    }

    float* kout = out + K_OFF;
    float* vout = out + V_OFF;
    #pragma unroll
    for (int i = 0; i < 4; ++i) {
        const int r = by * 64 + (ty << 2) + i;   // global row = b*S+s
        const int b = r >> 11, s = r & 2047;
        #pragma unroll
        for (int j = 0; j < 4; ++j) {
            const int c = bx * 64 + (tx << 2) + j;
            if (c < 2048) {
                const int sec = c >> 10;         // 0=q, 1=k
                const int cc  = c & 1023;
                const int h = cc >> 6, d2 = cc & 63;
                const float val = (acc[i][j] + bc[sec * 2048 + h * 128 + d2]) * fq[s * 64 + d2];
                const int o = ((b * 16 + h) * 2048 + s) * 128 + d2;
                if (sec == 0) { qws[o] = val;  qws[o + 64] = val; }
                else          { kout[o] = val; kout[o + 64] = val; }
            } else {
                const int cc = c - 2048;
                const int h = cc >> 7, d = cc & 127;
                vout[((b * 16 + h) * 2048 + s) * 128 + d] = acc[i][j] + bc[4096 + cc];
            }
        }
    }
}

// ---------------------------------------------------------------------------
// Kernel 2: flash attention, fp32. One block = 64 q rows of one (b,h).
// 256 threads: thread t -> q row (t>>2), slice lane c = t&3.
// d-partition is INTERLEAVED: lane c owns d = 16*w + 4*c + e (w=0..7,e=0..3)
// so the 4 slice-lanes' ds_read_b128 addresses hit disjoint bank quartets
// (conflict-free, 16-lane broadcast per address).
// ---------------------------------------------------------------------------
__global__ __launch_bounds__(256) void attn_kernel(
    const float* __restrict__ qws, const float* __restrict__ kbuf,
    const float* __restrict__ vbuf, float* __restrict__ y)
{
    __shared__ __align__(16) float kt[32][128];
    __shared__ __align__(16) float vt[32][128];

    const int t  = threadIdx.x;
    const int qb = blockIdx.x & 31;      // q block within head
    const int bh = blockIdx.x >> 5;      // b*16+h
    const int r  = t >> 2;               // q row in block
    const int c  = t & 3;                // slice lane
    const int s  = (qb << 6) + r;

    float qv[32];                        // qv[4*w+e] = q[d=16*w+4*c+e]
    {
        const float* qp = qws + (bh * 2048 + s) * 128 + (c << 2);
        #pragma unroll
        for (int w = 0; w < 8; ++w) {
            float4 v4 = *(const float4*)(qp + (w << 4));
            qv[4 * w] = v4.x; qv[4 * w + 1] = v4.y;
            qv[4 * w + 2] = v4.z; qv[4 * w + 3] = v4.w;
        }
    }

    float o[32];
    #pragma unroll
    for (int i = 0; i < 32; ++i) o[i] = 0.f;
    float m = -INFINITY, l = 0.f;

    const float* kb = kbuf + bh * (2048 * 128);
    const float* vb = vbuf + bh * (2048 * 128);

    for (int k0 = 0; k0 < 2048; k0 += 32) {
        #pragma unroll
        for (int p = 0; p < 4; ++p) {
            const int id = t + (p << 8);         // 0..1023
            const int kr = id >> 5, kc = (id & 31) << 2;
            *(float4*)(&kt[kr][kc]) = *(const float4*)(kb + (k0 + kr) * 128 + kc);
            *(float4*)(&vt[kr][kc]) = *(const float4*)(vb + (k0 + kr) * 128 + kc);
        }
        __syncthreads();

        float lg[32];
        for (int j = 0; j < 32; ++j) {
            float p = 0.f;
            const float* krow = &kt[j][c << 2];
            #pragma unroll
            for (int w = 0; w < 8; ++w) {
                float4 k4 = *(const float4*)(krow + (w << 4));
                p = fmaf(qv[4 * w],     k4.x, p);
                p = fmaf(qv[4 * w + 1], k4.y, p);
                p = fmaf(qv[4 * w + 2], k4.z, p);
                p = fmaf(qv[4 * w + 3], k4.w, p);
            }
            p += __shfl_xor(p, 1);
            p += __shfl_xor(p, 2);
            lg[j] = p * 0.08838834764831845f;   // 1/sqrt(128), applied after dot
        }

        float mx = m;
        #pragma unroll
        for (int j = 0; j < 32; ++j) mx = fmaxf(mx, lg[j]);
        const float alpha = expf(m - mx);       // 0 on first tile (m = -inf)
        m = mx;

        float psum = 0.f;
        for (int j = 0; j < 32; ++j) { lg[j] = expf(lg[j] - mx); psum += lg[j]; }
        l = l * alpha + psum;

        #pragma unroll
        for (int i = 0; i < 32; ++i) o[i] *= alpha;
        for (int j = 0; j < 32; ++j) {
            const float pj = lg[j];
            const float* vrow = &vt[j][c << 2];
            #pragma unroll
            for (int w = 0; w < 8; ++w) {
                float4 v4 = *(const float4*)(vrow + (w << 4));
                o[4 * w]     = fmaf(pj, v4.x, o[4 * w]);
                o[4 * w + 1] = fmaf(pj, v4.y, o[4 * w + 1]);
                o[4 * w + 2] = fmaf(pj, v4.z, o[4 * w + 2]);
                o[4 * w + 3] = fmaf(pj, v4.w, o[4 * w + 3]);
            }
        }
        __syncthreads();
    }

    const float inv = 1.f / l;
    const int b = bh >> 4, h = bh & 15;
    float* yp = y + (b * 2048 + s) * 2048 + h * 128 + (c << 2);
    #pragma unroll
    for (int w = 0; w < 8; ++w) {
        float4 v4;
        v4.x = o[4 * w] * inv; v4.y = o[4 * w + 1] * inv;
        v4.z = o[4 * w + 2] * inv; v4.w = o[4 * w + 3] * inv;
        *(float4*)(yp + (w << 4)) = v4;
    }
}

extern "C" void kernel_launch(void* const* d_in, const int* in_sizes, int n_in,
                              void* d_out, int out_size, void* d_ws, size_t ws_size,
                              hipStream_t stream)
{
    const float* x  = (const float*)d_in[0];   // (B,S,E) fp32
    const float* Wc = (const float*)d_in[1];   // (3E,E) fp32
    const float* bc = (const float*)d_in[2];   // (3E,)
    const float* fq = (const float*)d_in[3];   // (S, 64)
    float* out = (float*)d_out;
    float* qws = (float*)d_ws;                 // q, (B,H,S,D) fp32 = 64 MiB

    dim3 g1(64, 64);  // x: reduced-col tiles, y: row tiles
    gemm_rope_kernel<<<g1, 256, 0, stream>>>(x, Wc, bc, fq, qws, out);
    attn_kernel<<<1024, 256, 0, stream>>>(qws, out + K_OFF, out + V_OFF, out + Y_OFF);
}

// Round 3
// 2113.877 us; speedup vs baseline: 1.5892x; 1.4630x over previous
//
#include <hip/hip_runtime.h>
#include <hip/hip_fp16.h>
#include <math.h>

// Problem constants
#define S_LEN 2048
#define NHEAD 16
#define EMB   2048
#define HD    128
#define KDIM  2048
// d_out layout (floats): y | k | v
#define Y_OFF 0
#define K_OFF 8388608
#define V_OFF 16777216

// ---------------------------------------------------------------------------
// Kernel 1: qkv = x @ Wc^T + bc, fused with rope-scale + scatter (unchanged).
// ---------------------------------------------------------------------------
__global__ __launch_bounds__(256) void gemm_rope_kernel(
    const float* __restrict__ x, const float* __restrict__ Wc,
    const float* __restrict__ bc, const float* __restrict__ fq,
    float* __restrict__ qws, float* __restrict__ out)
{
    __shared__ __align__(16) float As[32][68];
    __shared__ __align__(16) float Bs[32][68];

    const int t  = threadIdx.x;
    const int bx = blockIdx.x;
    const int by = blockIdx.y;
    const int tx = t & 15, ty = t >> 4;

    float acc[4][4] = {{0.f, 0.f, 0.f, 0.f}, {0.f, 0.f, 0.f, 0.f},
                       {0.f, 0.f, 0.f, 0.f}, {0.f, 0.f, 0.f, 0.f}};

    for (int k0 = 0; k0 < KDIM; k0 += 32) {
        #pragma unroll
        for (int p = 0; p < 2; ++p) {
            const int id  = t + (p << 8);
            const int row = id >> 3;
            const int kc  = (id & 7) << 2;
            float4 va = *(const float4*)(x + (by * 64 + row) * KDIM + k0 + kc);
            As[kc + 0][row] = va.x; As[kc + 1][row] = va.y;
            As[kc + 2][row] = va.z; As[kc + 3][row] = va.w;

            const int c = bx * 64 + row;
            int srow;
            if (c < 1024)      srow = ((c >> 6) << 7) + (c & 63);
            else if (c < 2048) srow = 2048 + (((c - 1024) >> 6) << 7) + (c & 63);
            else               srow = 4096 + (c - 2048);
            float4 vb = *(const float4*)(Wc + srow * KDIM + k0 + kc);
            Bs[kc + 0][row] = vb.x; Bs[kc + 1][row] = vb.y;
            Bs[kc + 2][row] = vb.z; Bs[kc + 3][row] = vb.w;
        }
        __syncthreads();
        #pragma unroll
        for (int kk = 0; kk < 32; ++kk) {
            float4 a = *(const float4*)(&As[kk][ty << 2]);
            float4 b = *(const float4*)(&Bs[kk][tx << 2]);
            const float av[4] = {a.x, a.y, a.z, a.w};
            const float bv[4] = {b.x, b.y, b.z, b.w};
            #pragma unroll
            for (int i = 0; i < 4; ++i)
                #pragma unroll
                for (int j = 0; j < 4; ++j)
                    acc[i][j] = fmaf(av[i], bv[j], acc[i][j]);
        }
        __syncthreads();
    }

    float* kout = out + K_OFF;
    float* vout = out + V_OFF;
    #pragma unroll
    for (int i = 0; i < 4; ++i) {
        const int r = by * 64 + (ty << 2) + i;
        const int b = r >> 11, s = r & 2047;
        #pragma unroll
        for (int j = 0; j < 4; ++j) {
            const int c = bx * 64 + (tx << 2) + j;
            if (c < 2048) {
                const int sec = c >> 10;
                const int cc  = c & 1023;
                const int h = cc >> 6, d2 = cc & 63;
                const float val = (acc[i][j] + bc[sec * 2048 + h * 128 + d2]) * fq[s * 64 + d2];
                const int o = ((b * 16 + h) * 2048 + s) * 128 + d2;
                if (sec == 0) { qws[o] = val;  qws[o + 64] = val; }
                else          { kout[o] = val; kout[o + 64] = val; }
            } else {
                const int cc = c - 2048;
                const int h = cc >> 7, d = cc & 127;
                vout[((b * 16 + h) * 2048 + s) * 128 + d] = acc[i][j] + bc[4096 + cc];
            }
        }
    }
}

// ---------------------------------------------------------------------------
// Kernel 2: register-tiled flash attention, fp32 logits.
// Block: 256 threads (tr=t>>4 in 0..15, tc=t&15), QB=128 q-rows, KB=64 keys.
// Thread owns S[8 qr][4 key] (qr = tr*8+i, key = 4*tc+j) and
// O[8 qr][8 d] (d = 4*tc+e and 64+4*tc+e).
// LDS: Qt[d][qr] fp32 64KB | Ks[key][132] fp32 33KB | Vs[key][128] fp32 32KB
//      Ps[key][qr] fp16 16KB  -> 144KB total, 1 block/CU.
// ---------------------------------------------------------------------------
__global__ __launch_bounds__(256, 1) void attn_kernel(
    const float* __restrict__ qws, const float* __restrict__ kbuf,
    const float* __restrict__ vbuf, float* __restrict__ y)
{
    __shared__ __align__(16) float  Qt[128][128];  // [d][qr]
    __shared__ __align__(16) float  Ks[64][132];   // [key][d], padded (132%32==4 -> bank spread)
    __shared__ __align__(16) float  Vs[64][128];   // [key][d]
    __shared__ __align__(16) __half Ps[64][128];   // [key][qr]

    const int t   = threadIdx.x;
    const int bid = blockIdx.x;
    const int bh  = bid & 31;      // same-head blocks at stride 32 -> same XCD (mod 8)
    const int qb  = bid >> 5;      // 0..15
    const int tr  = t >> 4;
    const int tc  = t & 15;
    const int s0  = qb << 7;

    const float* qp = qws  + (size_t)bh * (2048 * 128);
    const float* kb = kbuf + (size_t)bh * (2048 * 128);
    const float* vb = vbuf + (size_t)bh * (2048 * 128);

    // ---- stage Q transposed: Qt[d][qr]
    {
        const int fi = t & 31;     // float4 index in row
        const int r0 = t >> 5;     // 0..7
        #pragma unroll
        for (int l = 0; l < 16; ++l) {
            const int qr = r0 + (l << 3);
            float4 v4 = *(const float4*)(qp + (size_t)(s0 + qr) * 128 + (fi << 2));
            Qt[(fi << 2) + 0][qr] = v4.x;
            Qt[(fi << 2) + 1][qr] = v4.y;
            Qt[(fi << 2) + 2][qr] = v4.z;
            Qt[(fi << 2) + 3][qr] = v4.w;
        }
    }

    float accO[8][8];
    #pragma unroll
    for (int i = 0; i < 8; ++i)
        #pragma unroll
        for (int j = 0; j < 8; ++j) accO[i][j] = 0.f;
    float mrow[8], lrow[8];
    #pragma unroll
    for (int i = 0; i < 8; ++i) { mrow[i] = -INFINITY; lrow[i] = 0.f; }

    const float scale = 0.08838834764831845f;  // 1/sqrt(128)

    for (int k0 = 0; k0 < 2048; k0 += 64) {
        __syncthreads();  // prev step3 done: safe to overwrite Ks/Vs/Ps

        // ---- stage K (padded) and V (natural): coalesced 1KB/wave rows
        {
            const int fi = t & 31;
            const int r0 = t >> 5;   // 0..7
            #pragma unroll
            for (int l = 0; l < 8; ++l) {
                const int key = r0 + (l << 3);
                const size_t g = (size_t)(k0 + key) * 128 + (fi << 2);
                *(float4*)(&Ks[key][fi << 2]) = *(const float4*)(kb + g);
                *(float4*)(&Vs[key][fi << 2]) = *(const float4*)(vb + g);
            }
        }
        __syncthreads();

        // ---- step 1: S[8][4] = Q . K^T (sequential-d fp32 fmaf chain)
        float sv[8][4];
        #pragma unroll
        for (int i = 0; i < 8; ++i)
            #pragma unroll
            for (int j = 0; j < 4; ++j) sv[i][j] = 0.f;

        #pragma unroll 4
        for (int d = 0; d < 128; ++d) {
            float4 a0 = *(const float4*)(&Qt[d][tr << 3]);
            float4 a1 = *(const float4*)(&Qt[d][(tr << 3) + 4]);
            const float av[8] = {a0.x, a0.y, a0.z, a0.w, a1.x, a1.y, a1.z, a1.w};
            float bv[4];
            #pragma unroll
            for (int j = 0; j < 4; ++j) bv[j] = Ks[(tc << 2) + j][d];
            #pragma unroll
            for (int i = 0; i < 8; ++i)
                #pragma unroll
                for (int j = 0; j < 4; ++j)
                    sv[i][j] = fmaf(av[i], bv[j], sv[i][j]);
        }

        // ---- softmax update (stats per q-row, reduced over 16 tc lanes)
        #pragma unroll
        for (int i = 0; i < 8; ++i) {
            #pragma unroll
            for (int j = 0; j < 4; ++j) sv[i][j] *= scale;
            float mx = fmaxf(fmaxf(sv[i][0], sv[i][1]), fmaxf(sv[i][2], sv[i][3]));
            mx = fmaxf(mx, __shfl_xor(mx, 1));
            mx = fmaxf(mx, __shfl_xor(mx, 2));
            mx = fmaxf(mx, __shfl_xor(mx, 4));
            mx = fmaxf(mx, __shfl_xor(mx, 8));
            const float mn = fmaxf(mrow[i], mx);
            const float al = __expf(mrow[i] - mn);   // 0 on first tile
            mrow[i] = mn;
            float ps = 0.f;
            #pragma unroll
            for (int j = 0; j < 4; ++j) {
                const float p = __expf(sv[i][j] - mn);
                sv[i][j] = p;
                ps += p;
            }
            ps += __shfl_xor(ps, 1);
            ps += __shfl_xor(ps, 2);
            ps += __shfl_xor(ps, 4);
            ps += __shfl_xor(ps, 8);
            lrow[i] = lrow[i] * al + ps;
            #pragma unroll
            for (int j = 0; j < 8; ++j) accO[i][j] *= al;
        }

        // ---- write P (fp16) to LDS: Ps[key][qr], 16B per key-column
        #pragma unroll
        for (int j = 0; j < 4; ++j) {
            __half2 h[4];
            #pragma unroll
            for (int q = 0; q < 4; ++q) {
                __half2 hh;
                hh.x = __float2half_rn(sv[2 * q][j]);
                hh.y = __float2half_rn(sv[2 * q + 1][j]);
                h[q] = hh;
            }
            *(float4*)(&Ps[(tc << 2) + j][tr << 3]) = *(float4*)h;
        }
        __syncthreads();

        // ---- step 3: O += P . V (sequential keys)
        for (int key = 0; key < 64; ++key) {
            float4 praw = *(const float4*)(&Ps[key][tr << 3]);
            const __half2* ph = (const __half2*)&praw;
            float pv[8];
            #pragma unroll
            for (int q = 0; q < 4; ++q) {
                pv[2 * q]     = __low2float(ph[q]);
                pv[2 * q + 1] = __high2float(ph[q]);
            }
            float4 v0 = *(const float4*)(&Vs[key][tc << 2]);
            float4 v1 = *(const float4*)(&Vs[key][64 + (tc << 2)]);
            const float vv[8] = {v0.x, v0.y, v0.z, v0.w, v1.x, v1.y, v1.z, v1.w};
            #pragma unroll
            for (int i = 0; i < 8; ++i)
                #pragma unroll
                for (int j = 0; j < 8; ++j)
                    accO[i][j] = fmaf(pv[i], vv[j], accO[i][j]);
        }
    }

    // ---- epilogue: normalize and store
    const int b = bh >> 4, h = bh & 15;
    #pragma unroll
    for (int i = 0; i < 8; ++i) {
        const float inv = 1.f / lrow[i];
        const int srow = s0 + (tr << 3) + i;
        float* yp = y + ((size_t)(b * 2048 + srow)) * 2048 + h * 128;
        float4 o0, o1;
        o0.x = accO[i][0] * inv; o0.y = accO[i][1] * inv;
        o0.z = accO[i][2] * inv; o0.w = accO[i][3] * inv;
        o1.x = accO[i][4] * inv; o1.y = accO[i][5] * inv;
        o1.z = accO[i][6] * inv; o1.w = accO[i][7] * inv;
        *(float4*)(yp + (tc << 2))      = o0;
        *(float4*)(yp + 64 + (tc << 2)) = o1;
    }
}

extern "C" void kernel_launch(void* const* d_in, const int* in_sizes, int n_in,
                              void* d_out, int out_size, void* d_ws, size_t ws_size,
                              hipStream_t stream)
{
    const float* x  = (const float*)d_in[0];
    const float* Wc = (const float*)d_in[1];
    const float* bc = (const float*)d_in[2];
    const float* fq = (const float*)d_in[3];
    float* out = (float*)d_out;
    float* qws = (float*)d_ws;   // q, (B,H,S,D) fp32 = 64 MiB

    dim3 g1(64, 64);
    gemm_rope_kernel<<<g1, 256, 0, stream>>>(x, Wc, bc, fq, qws, out);
    attn_kernel<<<512, 256, 0, stream>>>(qws, out + K_OFF, out + V_OFF, out + Y_OFF);
}